// Round 9
// baseline (126.143 us; speedup 1.0000x reference)
//
#include <hip/hip_runtime.h>

using bf16 = __bf16;
typedef __bf16 bf16x8 __attribute__((ext_vector_type(8)));
typedef __bf16 bf16x4 __attribute__((ext_vector_type(4)));
typedef float f32x4 __attribute__((ext_vector_type(4)));
typedef float f32x16 __attribute__((ext_vector_type(16)));

#define MFMA16(a, b, c) __builtin_amdgcn_mfma_f32_16x16x32_bf16((a), (b), (c), 0, 0, 0)
#define MFMA32(a, b, c) __builtin_amdgcn_mfma_f32_32x32x16_bf16((a), (b), (c), 0, 0, 0)

constexpr int S = 2048, DM = 512, H = 8, DK = 64, HD = 512;
constexpr int NBLK = 16, BLK = 128;
constexpr int Mrows = 8 * S;  // 16384
constexpr float LOG2E = 1.44269504088896340736f;

__device__ __forceinline__ void gll16(const void* g, void* l) {
  __builtin_amdgcn_global_load_lds((const __attribute__((address_space(1))) unsigned int*)g,
                                   (__attribute__((address_space(3))) unsigned int*)l, 16, 0, 0);
}

// ---------------- fp32 -> bf16 convert (hidden) ----------------
__global__ void k_conv(const float* __restrict__ x, bf16* __restrict__ y) {
  size_t i = ((size_t)blockIdx.x * 256 + threadIdx.x) * 8;
  float4 a = *(const float4*)(x + i);
  float4 b = *(const float4*)(x + i + 4);
  bf16x8 o;
  o[0] = (bf16)a.x; o[1] = (bf16)a.y; o[2] = (bf16)a.z; o[3] = (bf16)a.w;
  o[4] = (bf16)b.x; o[5] = (bf16)b.y; o[6] = (bf16)b.z; o[7] = (bf16)b.w;
  *(bf16x8*)(y + i) = o;
}

// ---------------- weight transpose + convert (all 4 weights, z-indexed) ----------------
__global__ void k_transw4(const float* __restrict__ W0, const float* __restrict__ W1,
                          const float* __restrict__ W2, const float* __restrict__ W3,
                          bf16* __restrict__ D0, bf16* __restrict__ D1,
                          bf16* __restrict__ D2, bf16* __restrict__ D3) {
  const int z = blockIdx.z;
  const float* W = (z == 0) ? W0 : (z == 1) ? W1 : (z == 2) ? W2 : W3;
  bf16* Wt = (z == 0) ? D0 : (z == 1) ? D1 : (z == 2) ? D2 : D3;
  __shared__ float tile[32][33];
  int k0 = blockIdx.x * 32, n0 = blockIdx.y * 32;
  int tx = threadIdx.x, ty = threadIdx.y;  // (32,8)
#pragma unroll
  for (int i = 0; i < 4; i++)
    tile[ty * 4 + i][tx] = W[(size_t)(k0 + ty * 4 + i) * 512 + n0 + tx];
  __syncthreads();
#pragma unroll
  for (int i = 0; i < 4; i++)
    Wt[(size_t)(n0 + ty * 4 + i) * 512 + k0 + tx] = (bf16)tile[tx][ty * 4 + i];
}

// ---------------- RoPE cos/sin table ----------------
__global__ void k_ctab(float2* __restrict__ ctab) {
  int idx = blockIdx.x * 256 + threadIdx.x;  // 65536 entries
  int s = idx >> 5, i = idx & 31;
  float invf = exp2f(-(float)i * (13.287712379549449f / 32.0f));  // 10000^(-i/32)
  float ang = (float)s * invf;
  ctab[idx] = make_float2(cosf(ang), sinf(ang));
}

// ---------------- 128x128x(K=512) bf16 GEMM (2-phase dbuf), QKV variant + fused RoPE ----
// 1-D grid 1536, XCD/L2-aware: XCD owns M-slice of 16 tiles; iterates (m,(z,y)) so the
// A-tile stays in its private L2 across the 12 (z,y) passes.
// z=0: Q (rope, *LOG2E) -> Qo flat.  z=1: K (rope) -> Ko flat.  z=2: V -> Vt[bh][d][s].
__global__ __launch_bounds__(256) void k_gemm_qkv(
    const bf16* __restrict__ Xb,
    const bf16* __restrict__ Wtq, const bf16* __restrict__ Wtk, const bf16* __restrict__ Wtv,
    bf16* __restrict__ Qo, bf16* __restrict__ Ko, bf16* __restrict__ Vt,
    const float2* __restrict__ ctab) {
  const int bid = blockIdx.x;
  const int xcd = bid & 7, i = bid >> 3;   // 192 blocks per XCD
  const int mloc = i / 12, zy = i % 12;
  const int z = zy >> 2, y = zy & 3;
  const bf16* Wt = (z == 0) ? Wtq : ((z == 1) ? Wtk : Wtv);
  bf16* dst = (z == 0) ? Qo : Ko;
  const float qscale = (z == 0) ? LOG2E : 1.0f;

  __shared__ __align__(16) char Asm2[2][8192];
  __shared__ __align__(16) char Bsm2[2][8192];

  const int t = threadIdx.x, l = t & 63, wid = t >> 6;
  const int l15 = l & 15, l4 = l >> 4;
  const int wm = wid >> 1, wn = wid & 1;
  const size_t arow0 = (size_t)(xcd * 16 + mloc) * 128;
  const size_t brow0 = (size_t)y * 128;

  f32x4 acc[4][4] = {};
  const int rs = wid * 16 + (l >> 2);          // linear dest row
  const int cs = (l & 3) ^ ((l >> 2) & 3);     // pre-swizzled source chunk

  auto stage = [&](int kt, int b) {
    const int k0 = kt * 32;
    gll16(Xb + (arow0 + rs) * 512 + k0 + cs * 8,      Asm2[b] + wid * 1024);
    gll16(Xb + (arow0 + 64 + rs) * 512 + k0 + cs * 8, Asm2[b] + 4096 + wid * 1024);
    gll16(Wt + (brow0 + rs) * 512 + k0 + cs * 8,      Bsm2[b] + wid * 1024);
    gll16(Wt + (brow0 + 64 + rs) * 512 + k0 + cs * 8, Bsm2[b] + 4096 + wid * 1024);
  };

  stage(0, 0);
  asm volatile("s_waitcnt vmcnt(0)" ::: "memory");
  __builtin_amdgcn_s_barrier();

  int cur = 0;
  for (int kt = 0; kt < 16; ++kt) {
    if (kt < 15) stage(kt + 1, cur ^ 1);
    bf16x8 af[4], bfr[4];
#pragma unroll
    for (int mi = 0; mi < 4; mi++) {
      int row = wm * 64 + mi * 16 + l15;
      af[mi] = *(const bf16x8*)(Asm2[cur] + row * 64 + ((l4 ^ (row & 3)) * 16));
    }
#pragma unroll
    for (int ni = 0; ni < 4; ni++) {
      int row = wn * 64 + ni * 16 + l15;
      bfr[ni] = *(const bf16x8*)(Bsm2[cur] + row * 64 + ((l4 ^ (row & 3)) * 16));
    }
#pragma unroll
    for (int mi = 0; mi < 4; mi++)
#pragma unroll
      for (int ni = 0; ni < 4; ni++)
        acc[mi][ni] = MFMA16(af[mi], bfr[ni], acc[mi][ni]);
    if (kt < 15) {
      asm volatile("s_waitcnt vmcnt(0)" ::: "memory");
      __builtin_amdgcn_s_barrier();
    }
    cur ^= 1;
  }

  if (z == 2) {
    // write V^T: Vt[(b*H + h)*64 + d][s], pack 4 consecutive s (r dim) per store
    const int b = (int)(arow0 >> 11);
#pragma unroll
    for (int mi = 0; mi < 4; mi++) {
      int scol = (int)(arow0 & 2047) + wm * 64 + mi * 16 + l4 * 4;
#pragma unroll
      for (int ni = 0; ni < 4; ni++) {
        int col = (int)brow0 + wn * 64 + ni * 16 + l15;
        int hh = col >> 6, dd = col & 63;
        bf16x4 pk = {(bf16)acc[mi][ni][0], (bf16)acc[mi][ni][1],
                     (bf16)acc[mi][ni][2], (bf16)acc[mi][ni][3]};
        *(bf16x4*)(Vt + ((size_t)((b * H + hh) * 64 + dd)) * 2048 + scol) = pk;
      }
    }
    return;
  }

#pragma unroll
  for (int mi = 0; mi < 4; mi++) {
#pragma unroll
    for (int r = 0; r < 4; r++) {
      int grow = (int)arow0 + wm * 64 + mi * 16 + l4 * 4 + r;
      size_t rowoff = (size_t)grow * 512 + brow0 + wn * 64;
      int s = grow & (S - 1);
      float2 cs0 = ctab[s * 32 + l15];
      float2 cs1 = ctab[s * 32 + 16 + l15];
#pragma unroll
      for (int ni = 0; ni < 4; ni++) {
        float a = acc[mi][ni][r];
        float b = acc[mi][ni ^ 2][r];
        float2 cc = (ni & 1) ? cs1 : cs0;
        float val = (ni < 2) ? (a * cc.x - b * cc.y) : (a * cc.x + b * cc.y);
        dst[rowoff + ni * 16 + l15] = (bf16)(val * qscale);
      }
    }
  }
}

// ---------------- output projection GEMM (2-phase dbuf, L2 swizzle) -> fp32 ----------------
__global__ __launch_bounds__(256) void k_gemm_out(
    const bf16* __restrict__ A, const bf16* __restrict__ Wt, float* __restrict__ out) {
  const int bid = blockIdx.x;
  const int xcd = bid & 7, i = bid >> 3;  // 64 per XCD: 16 m x 4 y
  __shared__ __align__(16) char Asm2[2][8192];
  __shared__ __align__(16) char Bsm2[2][8192];

  const int t = threadIdx.x, l = t & 63, wid = t >> 6;
  const int l15 = l & 15, l4 = l >> 4;
  const int wm = wid >> 1, wn = wid & 1;
  const size_t arow0 = (size_t)(xcd * 16 + (i >> 2)) * 128;
  const size_t brow0 = (size_t)(i & 3) * 128;

  f32x4 acc[4][4] = {};
  const int rs = wid * 16 + (l >> 2);
  const int cs = (l & 3) ^ ((l >> 2) & 3);

  auto stage = [&](int kt, int b) {
    const int k0 = kt * 32;
    gll16(A + (arow0 + rs) * 512 + k0 + cs * 8,       Asm2[b] + wid * 1024);
    gll16(A + (arow0 + 64 + rs) * 512 + k0 + cs * 8,  Asm2[b] + 4096 + wid * 1024);
    gll16(Wt + (brow0 + rs) * 512 + k0 + cs * 8,      Bsm2[b] + wid * 1024);
    gll16(Wt + (brow0 + 64 + rs) * 512 + k0 + cs * 8, Bsm2[b] + 4096 + wid * 1024);
  };

  stage(0, 0);
  asm volatile("s_waitcnt vmcnt(0)" ::: "memory");
  __builtin_amdgcn_s_barrier();

  int cur = 0;
  for (int kt = 0; kt < 16; ++kt) {
    if (kt < 15) stage(kt + 1, cur ^ 1);
    bf16x8 af[4], bfr[4];
#pragma unroll
    for (int mi = 0; mi < 4; mi++) {
      int row = wm * 64 + mi * 16 + l15;
      af[mi] = *(const bf16x8*)(Asm2[cur] + row * 64 + ((l4 ^ (row & 3)) * 16));
    }
#pragma unroll
    for (int ni = 0; ni < 4; ni++) {
      int row = wn * 64 + ni * 16 + l15;
      bfr[ni] = *(const bf16x8*)(Bsm2[cur] + row * 64 + ((l4 ^ (row & 3)) * 16));
    }
#pragma unroll
    for (int mi = 0; mi < 4; mi++)
#pragma unroll
      for (int ni = 0; ni < 4; ni++)
        acc[mi][ni] = MFMA16(af[mi], bfr[ni], acc[mi][ni]);
    if (kt < 15) {
      asm volatile("s_waitcnt vmcnt(0)" ::: "memory");
      __builtin_amdgcn_s_barrier();
    }
    cur ^= 1;
  }

#pragma unroll
  for (int mi = 0; mi < 4; mi++)
#pragma unroll
    for (int r = 0; r < 4; r++) {
      int grow = (int)arow0 + wm * 64 + mi * 16 + l4 * 4 + r;
      size_t rowoff = (size_t)grow * 512 + brow0 + wn * 64;
#pragma unroll
      for (int ni = 0; ni < 4; ni++)
        out[rowoff + ni * 16 + l15] = acc[mi][ni][r];
    }
}

// ---------------- block-banded flash attention: software-pipelined, register-only ----
// 1024 blocks (XCD-swizzled), 256 thr = 4 waves x 32 q-rows. 9 single-chunk steps.
// Pipeline: K(c+1) + V(c) issued at step top (sched_barrier pins them above compute);
// QK consumes K(c) already in registers. P^T built in-register (cvt_pk + shfl_xor 32).
// Q pre-scaled by LOG2E (exp2 domain). Defer-max: skip rescale unless max grows by >8.
__global__ __launch_bounds__(256, 4) void k_attn(
    const bf16* __restrict__ Q, const bf16* __restrict__ K, const bf16* __restrict__ Vt,
    bf16* __restrict__ O) {
  // XCD swizzle: XCD x owns logical ids [x*128, x*128+128) = one full batch
  const int bid = blockIdx.x;
  const int swz = (bid & 7) * 128 + (bid >> 3);
  const int nb = swz & 15, h = (swz >> 4) & 7, bb = swz >> 7;
  const int t = threadIdx.x, l = t & 63, w = t >> 6;
  const int q31 = l & 31, hi = l >> 5;

  const int bh = bb * H + h;
  const size_t qrow = (size_t)bb * S + nb * BLK + w * 32 + q31;

  // Q B-frags: col q = l&31, k(dk) = ks*16 + hi*8 + j
  const bf16* Qp = Q + qrow * HD + h * DK + hi * 8;
  bf16x8 qb[4];
#pragma unroll
  for (int ks = 0; ks < 4; ks++) qb[ks] = *(const bf16x8*)(Qp + ks * 16);

  f32x16 o0 = {}, o1 = {};  // O^T[d][q]: q = l&31, d = dt*32 + (rg&3)+8*(rg>>2)+4*hi
  float mrun = -3e38f, lrun = 0.f;

  const bf16* Kbase = K + (size_t)bb * S * HD + h * DK + hi * 8;
  const bf16* Vbase = Vt + ((size_t)bh * 64 + q31) * 2048 + hi * 8;
  const int s0 = nb * BLK + w * 32 - 128;  // window start (chunk 0), 9 chunks of 32

  auto kcl = [](int kg) { return kg < 0 ? 0 : (kg > S - 32 ? S - 32 : kg); };

  // prologue: preload K chunk 0
  bf16x8 kcur0, kcur1, kcur2, kcur3;
  {
    const bf16* Kp = Kbase + (size_t)(kcl(s0) + q31) * HD;
    kcur0 = *(const bf16x8*)(Kp);
    kcur1 = *(const bf16x8*)(Kp + 16);
    kcur2 = *(const bf16x8*)(Kp + 32);
    kcur3 = *(const bf16x8*)(Kp + 48);
  }

#pragma unroll
  for (int c = 0; c < 9; ++c) {
    const int kg = s0 + c * 32;
    const int kcc = kcl(kg);
    const int kcn = kcl(s0 + (c + 1) * 32);

    // issue V(c) loads
    const bf16* Vp = Vbase + kcc;
    bf16x8 v0 = *(const bf16x8*)(Vp);
    bf16x8 v1 = *(const bf16x8*)(Vp + 16);
    bf16x8 v2 = *(const bf16x8*)(Vp + 32 * 2048);
    bf16x8 v3 = *(const bf16x8*)(Vp + 32 * 2048 + 16);
    // issue K(c+1) loads (uniform; clamped at c==8)
    const bf16* Kpn = Kbase + (size_t)(kcn + q31) * HD;
    bf16x8 kn0 = *(const bf16x8*)(Kpn);
    bf16x8 kn1 = *(const bf16x8*)(Kpn + 16);
    bf16x8 kn2 = *(const bf16x8*)(Kpn + 32);
    bf16x8 kn3 = *(const bf16x8*)(Kpn + 48);
    __builtin_amdgcn_sched_barrier(0);  // pin load issue above the compute phase

    // QK^T with K(c) already in registers
    f32x16 a = {};
    a = MFMA32(kcur0, qb[0], a);
    a = MFMA32(kcur1, qb[1], a);
    a = MFMA32(kcur2, qb[2], a);
    a = MFMA32(kcur3, qb[3], a);

    // band mask: key = kg + (rg&3)+8*(rg>>2)+4*hi, q col = q31
    if (kg != kcc) {
#pragma unroll
      for (int rg = 0; rg < 16; rg++) a[rg] = -1e30f;  // clamped chunk: fully invalid
    } else if (c == 0) {
#pragma unroll
      for (int rg = 0; rg < 16; rg++) {
        int kk = (rg & 3) + 8 * (rg >> 2) + 4 * hi;
        if (kk < q31) a[rg] = -1e30f;  // valid iff kk >= q
      }
    } else if (c == 8) {
#pragma unroll
      for (int rg = 0; rg < 16; rg++) {
        int kk = (rg & 3) + 8 * (rg >> 2) + 4 * hi;
        if (kk > q31) a[rg] = -1e30f;  // valid iff kk <= q
      }
    }

    // chunk max (in-lane tree + half-wave combine)
    f32x16 mx = a;
#pragma unroll
    for (int sl = 8; sl >= 1; sl >>= 1)
#pragma unroll
      for (int i2 = 0; i2 < sl; i2++) mx[i2] = fmaxf(mx[i2], mx[i2 + sl]);
    const float pm = fmaxf(mx[0], __shfl_xor(mx[0], 32));

    // defer-max: rescale only if max grew by > 8 (wave-uniform vote)
    if (!__all(pm - mrun <= 8.0f)) {
      const float mnew = fmaxf(mrun, pm);
      const float alpha = exp2f(mrun - mnew);
      lrun *= alpha;
#pragma unroll
      for (int rg = 0; rg < 16; rg++) { o0[rg] *= alpha; o1[rg] *= alpha; }
      mrun = mnew;
    }

    float rsum = 0.f;
#pragma unroll
    for (int rg = 0; rg < 16; rg++) { a[rg] = exp2f(a[rg] - mrun); rsum += a[rg]; }
    rsum += __shfl_xor(rsum, 32);
    lrun += rsum;

    // P^T B-frags in-register: cvt_pk words then half-wave exchange via shfl_xor(32)
    unsigned int Wd[4][2];
#pragma unroll
    for (int aa = 0; aa < 4; aa++)
#pragma unroll
      for (int b2 = 0; b2 < 2; b2++) {
        unsigned int wd;
        asm("v_cvt_pk_bf16_f32 %0, %1, %2" : "=v"(wd) : "v"(a[4 * aa + 2 * b2]), "v"(a[4 * aa + 2 * b2 + 1]));
        Wd[aa][b2] = wd;
      }
    bf16x8 pf[2];
#pragma unroll
    for (int ks = 0; ks < 2; ks++) {
      union { unsigned int u[4]; bf16x8 v; } cvt;
#pragma unroll
      for (int b2 = 0; b2 < 2; b2++) {
        unsigned int low_w = Wd[2 * ks][b2];      // keys 16ks + 4hi + 2b
        unsigned int hi_w  = Wd[2 * ks + 1][b2];  // keys 16ks + 8 + 4hi + 2b
        unsigned int msg = hi ? low_w : hi_w;     // send what the other half needs
        unsigned int rec = __shfl_xor(msg, 32);
        cvt.u[b2]     = hi ? rec : low_w;         // keys 16ks + 8hi + 2b
        cvt.u[2 + b2] = hi ? hi_w : rec;          // keys 16ks + 8hi + 4 + 2b
      }
      pf[ks] = cvt.v;
    }

    // PV with V(c) (loads have had QK+softmax to land)
    o0 = MFMA32(v0, pf[0], o0);
    o0 = MFMA32(v1, pf[1], o0);
    o1 = MFMA32(v2, pf[0], o1);
    o1 = MFMA32(v3, pf[1], o1);

    // rotate K pipeline
    kcur0 = kn0; kcur1 = kn1; kcur2 = kn2; kcur3 = kn3;
  }

  const float inv = 1.0f / lrun;
  bf16* Op = O + qrow * HD + h * DK + 4 * hi;
#pragma unroll
  for (int dt = 0; dt < 2; dt++) {
    const f32x16 oo = dt ? o1 : o0;
#pragma unroll
    for (int a2 = 0; a2 < 4; a2++) {
      bf16x4 ob = {(bf16)(oo[4 * a2 + 0] * inv), (bf16)(oo[4 * a2 + 1] * inv),
                   (bf16)(oo[4 * a2 + 2] * inv), (bf16)(oo[4 * a2 + 3] * inv)};
      *(bf16x4*)(Op + dt * 32 + 8 * a2) = ob;  // d = dt*32 + 8a + 4hi + (0..3)
    }
  }
}

extern "C" void kernel_launch(void* const* d_in, const int* in_sizes, int n_in,
                              void* d_out, int out_size, void* d_ws, size_t ws_size,
                              hipStream_t stream) {
  const float* hs = (const float*)d_in[0];
  const float* Wq = (const float*)d_in[1];
  const float* Wk = (const float*)d_in[2];
  const float* Wv = (const float*)d_in[3];
  const float* Wo = (const float*)d_in[4];
  float* out = (float*)d_out;

  char* ws = (char*)d_ws;
  const size_t MB = 1u << 20;
  bf16* Xb = (bf16*)(ws);                 // 16 MB, reused as attention output
  bf16* Qb = (bf16*)(ws + 16 * MB);
  bf16* Kb = (bf16*)(ws + 32 * MB);
  bf16* Vt = (bf16*)(ws + 48 * MB);       // V^T [64 bh][64 d][2048 s]
  bf16* Wtq = (bf16*)(ws + 64 * MB);
  bf16* Wtk = Wtq + 512 * 512;
  bf16* Wtv = Wtk + 512 * 512;
  bf16* Wto = Wtv + 512 * 512;
  float2* ctab = (float2*)(ws + 64 * MB + 4 * 512 * 512 * sizeof(bf16));
  bf16* AO = Xb;

  k_conv<<<dim3(Mrows * DM / (256 * 8)), dim3(256), 0, stream>>>(hs, Xb);
  k_transw4<<<dim3(16, 16, 4), dim3(32, 8), 0, stream>>>(Wq, Wk, Wv, Wo, Wtq, Wtk, Wtv, Wto);
  k_ctab<<<dim3(S * 32 / 256), dim3(256), 0, stream>>>(ctab);
  k_gemm_qkv<<<dim3(1536), dim3(256), 0, stream>>>(Xb, Wtq, Wtk, Wtv, Qb, Kb, Vt, ctab);
  k_attn<<<dim3(NBLK * H * 8), dim3(256), 0, stream>>>(Qb, Kb, Vt, AO);
  k_gemm_out<<<dim3(512), dim3(256), 0, stream>>>(AO, Wto, out);
}

// Round 10
// 122.900 us; speedup vs baseline: 1.0264x; 1.0264x over previous
//
#include <hip/hip_runtime.h>

using bf16 = __bf16;
typedef __bf16 bf16x8 __attribute__((ext_vector_type(8)));
typedef __bf16 bf16x4 __attribute__((ext_vector_type(4)));
typedef float f32x4 __attribute__((ext_vector_type(4)));
typedef float f32x16 __attribute__((ext_vector_type(16)));

#define MFMA16(a, b, c) __builtin_amdgcn_mfma_f32_16x16x32_bf16((a), (b), (c), 0, 0, 0)
#define MFMA32(a, b, c) __builtin_amdgcn_mfma_f32_32x32x16_bf16((a), (b), (c), 0, 0, 0)

constexpr int S = 2048, DM = 512, H = 8, DK = 64, HD = 512;
constexpr int NBLK = 16, BLK = 128;
constexpr int Mrows = 8 * S;  // 16384
constexpr float LOG2E = 1.44269504088896340736f;

__device__ __forceinline__ void gll16(const void* g, void* l) {
  __builtin_amdgcn_global_load_lds((const __attribute__((address_space(1))) unsigned int*)g,
                                   (__attribute__((address_space(3))) unsigned int*)l, 16, 0, 0);
}

// ---------------- fp32 -> bf16 convert (hidden) ----------------
__global__ void k_conv(const float* __restrict__ x, bf16* __restrict__ y) {
  size_t i = ((size_t)blockIdx.x * 256 + threadIdx.x) * 8;
  float4 a = *(const float4*)(x + i);
  float4 b = *(const float4*)(x + i + 4);
  bf16x8 o;
  o[0] = (bf16)a.x; o[1] = (bf16)a.y; o[2] = (bf16)a.z; o[3] = (bf16)a.w;
  o[4] = (bf16)b.x; o[5] = (bf16)b.y; o[6] = (bf16)b.z; o[7] = (bf16)b.w;
  *(bf16x8*)(y + i) = o;
}

// ---------------- weight transpose + convert (all 4 weights, z-indexed) ----------------
__global__ void k_transw4(const float* __restrict__ W0, const float* __restrict__ W1,
                          const float* __restrict__ W2, const float* __restrict__ W3,
                          bf16* __restrict__ D0, bf16* __restrict__ D1,
                          bf16* __restrict__ D2, bf16* __restrict__ D3) {
  const int z = blockIdx.z;
  const float* W = (z == 0) ? W0 : (z == 1) ? W1 : (z == 2) ? W2 : W3;
  bf16* Wt = (z == 0) ? D0 : (z == 1) ? D1 : (z == 2) ? D2 : D3;
  __shared__ float tile[32][33];
  int k0 = blockIdx.x * 32, n0 = blockIdx.y * 32;
  int tx = threadIdx.x, ty = threadIdx.y;  // (32,8)
#pragma unroll
  for (int i = 0; i < 4; i++)
    tile[ty * 4 + i][tx] = W[(size_t)(k0 + ty * 4 + i) * 512 + n0 + tx];
  __syncthreads();
#pragma unroll
  for (int i = 0; i < 4; i++)
    Wt[(size_t)(n0 + ty * 4 + i) * 512 + k0 + tx] = (bf16)tile[tx][ty * 4 + i];
}

// ---------------- RoPE cos/sin table ----------------
__global__ void k_ctab(float2* __restrict__ ctab) {
  int idx = blockIdx.x * 256 + threadIdx.x;  // 65536 entries
  int s = idx >> 5, i = idx & 31;
  float invf = exp2f(-(float)i * (13.287712379549449f / 32.0f));  // 10000^(-i/32)
  float ang = (float)s * invf;
  ctab[idx] = make_float2(cosf(ang), sinf(ang));
}

// ---------------- 128x128x(K=512) bf16 GEMM, 3-stage pipeline + counted vmcnt ----------
// Swizzle f(row)=(row>>2)&3 -> 2-way bank aliasing (free) instead of 4-way.
// 1-D grid 1536, XCD/L2-aware: XCD owns M-slice; iterates (m,(z,y)) for A-tile L2 reuse.
// z=0: Q (rope, *LOG2E) -> Qo flat.  z=1: K (rope) -> Ko flat.  z=2: V -> Vt[bh][d][s].
__global__ __launch_bounds__(256) void k_gemm_qkv(
    const bf16* __restrict__ Xb,
    const bf16* __restrict__ Wtq, const bf16* __restrict__ Wtk, const bf16* __restrict__ Wtv,
    bf16* __restrict__ Qo, bf16* __restrict__ Ko, bf16* __restrict__ Vt,
    const float2* __restrict__ ctab) {
  const int bid = blockIdx.x;
  const int xcd = bid & 7, i = bid >> 3;   // 192 blocks per XCD
  const int mloc = i / 12, zy = i % 12;
  const int z = zy >> 2, y = zy & 3;
  const bf16* Wt = (z == 0) ? Wtq : ((z == 1) ? Wtk : Wtv);
  bf16* dst = (z == 0) ? Qo : Ko;
  const float qscale = (z == 0) ? LOG2E : 1.0f;

  __shared__ __align__(16) char Asm3[3][8192];
  __shared__ __align__(16) char Bsm3[3][8192];

  const int t = threadIdx.x, l = t & 63, wid = t >> 6;
  const int l15 = l & 15, l4 = l >> 4;
  const int wm = wid >> 1, wn = wid & 1;
  const size_t arow0 = (size_t)(xcd * 16 + mloc) * 128;
  const size_t brow0 = (size_t)y * 128;

  f32x4 acc[4][4] = {};
  const int rs = wid * 16 + (l >> 2);          // linear dest row
  const int cs = (l & 3) ^ (l >> 4);           // pre-swizzled source chunk, f(row)=(row>>2)&3

  auto stage = [&](int kt, int b) {
    const int k0 = kt * 32;
    gll16(Xb + (arow0 + rs) * 512 + k0 + cs * 8,      Asm3[b] + wid * 1024);
    gll16(Xb + (arow0 + 64 + rs) * 512 + k0 + cs * 8, Asm3[b] + 4096 + wid * 1024);
    gll16(Wt + (brow0 + rs) * 512 + k0 + cs * 8,      Bsm3[b] + wid * 1024);
    gll16(Wt + (brow0 + 64 + rs) * 512 + k0 + cs * 8, Bsm3[b] + 4096 + wid * 1024);
  };

  stage(0, 0);
  stage(1, 1);
  asm volatile("s_waitcnt vmcnt(4)" ::: "memory");
  __builtin_amdgcn_s_barrier();

  int cur = 0;
  for (int kt = 0; kt < 16; ++kt) {
    if (kt + 2 <= 15) stage(kt + 2, (kt + 2) % 3);
    bf16x8 af[4], bfr[4];
#pragma unroll
    for (int mi = 0; mi < 4; mi++) {
      int row = wm * 64 + mi * 16 + l15;
      af[mi] = *(const bf16x8*)(Asm3[cur] + row * 64 + ((l4 ^ (l15 >> 2)) * 16));
    }
#pragma unroll
    for (int ni = 0; ni < 4; ni++) {
      int row = wn * 64 + ni * 16 + l15;
      bfr[ni] = *(const bf16x8*)(Bsm3[cur] + row * 64 + ((l4 ^ (l15 >> 2)) * 16));
    }
#pragma unroll
    for (int mi = 0; mi < 4; mi++)
#pragma unroll
      for (int ni = 0; ni < 4; ni++)
        acc[mi][ni] = MFMA16(af[mi], bfr[ni], acc[mi][ni]);
    if (kt < 15) {
      if (kt < 14) asm volatile("s_waitcnt vmcnt(4)" ::: "memory");
      else         asm volatile("s_waitcnt vmcnt(0)" ::: "memory");
      __builtin_amdgcn_s_barrier();
    }
    cur = (cur == 2) ? 0 : cur + 1;
  }

  if (z == 2) {
    // write V^T: Vt[(b*H + h)*64 + d][s], pack 4 consecutive s (r dim) per store
    const int b = (int)(arow0 >> 11);
#pragma unroll
    for (int mi = 0; mi < 4; mi++) {
      int scol = (int)(arow0 & 2047) + wm * 64 + mi * 16 + l4 * 4;
#pragma unroll
      for (int ni = 0; ni < 4; ni++) {
        int col = (int)brow0 + wn * 64 + ni * 16 + l15;
        int hh = col >> 6, dd = col & 63;
        bf16x4 pk = {(bf16)acc[mi][ni][0], (bf16)acc[mi][ni][1],
                     (bf16)acc[mi][ni][2], (bf16)acc[mi][ni][3]};
        *(bf16x4*)(Vt + ((size_t)((b * H + hh) * 64 + dd)) * 2048 + scol) = pk;
      }
    }
    return;
  }

#pragma unroll
  for (int mi = 0; mi < 4; mi++) {
#pragma unroll
    for (int r = 0; r < 4; r++) {
      int grow = (int)arow0 + wm * 64 + mi * 16 + l4 * 4 + r;
      size_t rowoff = (size_t)grow * 512 + brow0 + wn * 64;
      int s = grow & (S - 1);
      float2 cs0 = ctab[s * 32 + l15];
      float2 cs1 = ctab[s * 32 + 16 + l15];
#pragma unroll
      for (int ni = 0; ni < 4; ni++) {
        float a = acc[mi][ni][r];
        float b = acc[mi][ni ^ 2][r];
        float2 cc = (ni & 1) ? cs1 : cs0;
        float val = (ni < 2) ? (a * cc.x - b * cc.y) : (a * cc.x + b * cc.y);
        dst[rowoff + ni * 16 + l15] = (bf16)(val * qscale);
      }
    }
  }
}

// ---------------- output projection GEMM (3-stage pipeline, L2 swizzle) -> fp32 --------
__global__ __launch_bounds__(256) void k_gemm_out(
    const bf16* __restrict__ A, const bf16* __restrict__ Wt, float* __restrict__ out) {
  const int bid = blockIdx.x;
  const int xcd = bid & 7, i = bid >> 3;  // 64 per XCD: 16 m x 4 y
  __shared__ __align__(16) char Asm3[3][8192];
  __shared__ __align__(16) char Bsm3[3][8192];

  const int t = threadIdx.x, l = t & 63, wid = t >> 6;
  const int l15 = l & 15, l4 = l >> 4;
  const int wm = wid >> 1, wn = wid & 1;
  const size_t arow0 = (size_t)(xcd * 16 + (i >> 2)) * 128;
  const size_t brow0 = (size_t)(i & 3) * 128;

  f32x4 acc[4][4] = {};
  const int rs = wid * 16 + (l >> 2);
  const int cs = (l & 3) ^ (l >> 4);

  auto stage = [&](int kt, int b) {
    const int k0 = kt * 32;
    gll16(A + (arow0 + rs) * 512 + k0 + cs * 8,       Asm3[b] + wid * 1024);
    gll16(A + (arow0 + 64 + rs) * 512 + k0 + cs * 8,  Asm3[b] + 4096 + wid * 1024);
    gll16(Wt + (brow0 + rs) * 512 + k0 + cs * 8,      Bsm3[b] + wid * 1024);
    gll16(Wt + (brow0 + 64 + rs) * 512 + k0 + cs * 8, Bsm3[b] + 4096 + wid * 1024);
  };

  stage(0, 0);
  stage(1, 1);
  asm volatile("s_waitcnt vmcnt(4)" ::: "memory");
  __builtin_amdgcn_s_barrier();

  int cur = 0;
  for (int kt = 0; kt < 16; ++kt) {
    if (kt + 2 <= 15) stage(kt + 2, (kt + 2) % 3);
    bf16x8 af[4], bfr[4];
#pragma unroll
    for (int mi = 0; mi < 4; mi++) {
      int row = wm * 64 + mi * 16 + l15;
      af[mi] = *(const bf16x8*)(Asm3[cur] + row * 64 + ((l4 ^ (l15 >> 2)) * 16));
    }
#pragma unroll
    for (int ni = 0; ni < 4; ni++) {
      int row = wn * 64 + ni * 16 + l15;
      bfr[ni] = *(const bf16x8*)(Bsm3[cur] + row * 64 + ((l4 ^ (l15 >> 2)) * 16));
    }
#pragma unroll
    for (int mi = 0; mi < 4; mi++)
#pragma unroll
      for (int ni = 0; ni < 4; ni++)
        acc[mi][ni] = MFMA16(af[mi], bfr[ni], acc[mi][ni]);
    if (kt < 15) {
      if (kt < 14) asm volatile("s_waitcnt vmcnt(4)" ::: "memory");
      else         asm volatile("s_waitcnt vmcnt(0)" ::: "memory");
      __builtin_amdgcn_s_barrier();
    }
    cur = (cur == 2) ? 0 : cur + 1;
  }

#pragma unroll
  for (int mi = 0; mi < 4; mi++)
#pragma unroll
    for (int r = 0; r < 4; r++) {
      int grow = (int)arow0 + wm * 64 + mi * 16 + l4 * 4 + r;
      size_t rowoff = (size_t)grow * 512 + brow0 + wn * 64;
#pragma unroll
      for (int ni = 0; ni < 4; ni++)
        out[rowoff + ni * 16 + l15] = acc[mi][ni][r];
    }
}

// ---------------- block-banded flash attention: software-pipelined, register-only ----
// (unchanged from R9 — frozen this round)
__global__ __launch_bounds__(256, 4) void k_attn(
    const bf16* __restrict__ Q, const bf16* __restrict__ K, const bf16* __restrict__ Vt,
    bf16* __restrict__ O) {
  const int bid = blockIdx.x;
  const int swz = (bid & 7) * 128 + (bid >> 3);
  const int nb = swz & 15, h = (swz >> 4) & 7, bb = swz >> 7;
  const int t = threadIdx.x, l = t & 63, w = t >> 6;
  const int q31 = l & 31, hi = l >> 5;

  const int bh = bb * H + h;
  const size_t qrow = (size_t)bb * S + nb * BLK + w * 32 + q31;

  const bf16* Qp = Q + qrow * HD + h * DK + hi * 8;
  bf16x8 qb[4];
#pragma unroll
  for (int ks = 0; ks < 4; ks++) qb[ks] = *(const bf16x8*)(Qp + ks * 16);

  f32x16 o0 = {}, o1 = {};  // O^T[d][q]: q = l&31, d = dt*32 + (rg&3)+8*(rg>>2)+4*hi
  float mrun = -3e38f, lrun = 0.f;

  const bf16* Kbase = K + (size_t)bb * S * HD + h * DK + hi * 8;
  const bf16* Vbase = Vt + ((size_t)bh * 64 + q31) * 2048 + hi * 8;
  const int s0 = nb * BLK + w * 32 - 128;  // window start (chunk 0), 9 chunks of 32

  auto kcl = [](int kg) { return kg < 0 ? 0 : (kg > S - 32 ? S - 32 : kg); };

  bf16x8 kcur0, kcur1, kcur2, kcur3;
  {
    const bf16* Kp = Kbase + (size_t)(kcl(s0) + q31) * HD;
    kcur0 = *(const bf16x8*)(Kp);
    kcur1 = *(const bf16x8*)(Kp + 16);
    kcur2 = *(const bf16x8*)(Kp + 32);
    kcur3 = *(const bf16x8*)(Kp + 48);
  }

#pragma unroll
  for (int c = 0; c < 9; ++c) {
    const int kg = s0 + c * 32;
    const int kcc = kcl(kg);
    const int kcn = kcl(s0 + (c + 1) * 32);

    const bf16* Vp = Vbase + kcc;
    bf16x8 v0 = *(const bf16x8*)(Vp);
    bf16x8 v1 = *(const bf16x8*)(Vp + 16);
    bf16x8 v2 = *(const bf16x8*)(Vp + 32 * 2048);
    bf16x8 v3 = *(const bf16x8*)(Vp + 32 * 2048 + 16);
    const bf16* Kpn = Kbase + (size_t)(kcn + q31) * HD;
    bf16x8 kn0 = *(const bf16x8*)(Kpn);
    bf16x8 kn1 = *(const bf16x8*)(Kpn + 16);
    bf16x8 kn2 = *(const bf16x8*)(Kpn + 32);
    bf16x8 kn3 = *(const bf16x8*)(Kpn + 48);
    __builtin_amdgcn_sched_barrier(0);

    f32x16 a = {};
    a = MFMA32(kcur0, qb[0], a);
    a = MFMA32(kcur1, qb[1], a);
    a = MFMA32(kcur2, qb[2], a);
    a = MFMA32(kcur3, qb[3], a);

    if (kg != kcc) {
#pragma unroll
      for (int rg = 0; rg < 16; rg++) a[rg] = -1e30f;
    } else if (c == 0) {
#pragma unroll
      for (int rg = 0; rg < 16; rg++) {
        int kk = (rg & 3) + 8 * (rg >> 2) + 4 * hi;
        if (kk < q31) a[rg] = -1e30f;
      }
    } else if (c == 8) {
#pragma unroll
      for (int rg = 0; rg < 16; rg++) {
        int kk = (rg & 3) + 8 * (rg >> 2) + 4 * hi;
        if (kk > q31) a[rg] = -1e30f;
      }
    }

    f32x16 mx = a;
#pragma unroll
    for (int sl = 8; sl >= 1; sl >>= 1)
#pragma unroll
      for (int i2 = 0; i2 < sl; i2++) mx[i2] = fmaxf(mx[i2], mx[i2 + sl]);
    const float pm = fmaxf(mx[0], __shfl_xor(mx[0], 32));

    if (!__all(pm - mrun <= 8.0f)) {
      const float mnew = fmaxf(mrun, pm);
      const float alpha = exp2f(mrun - mnew);
      lrun *= alpha;
#pragma unroll
      for (int rg = 0; rg < 16; rg++) { o0[rg] *= alpha; o1[rg] *= alpha; }
      mrun = mnew;
    }

    float rsum = 0.f;
#pragma unroll
    for (int rg = 0; rg < 16; rg++) { a[rg] = exp2f(a[rg] - mrun); rsum += a[rg]; }
    rsum += __shfl_xor(rsum, 32);
    lrun += rsum;

    unsigned int Wd[4][2];
#pragma unroll
    for (int aa = 0; aa < 4; aa++)
#pragma unroll
      for (int b2 = 0; b2 < 2; b2++) {
        unsigned int wd;
        asm("v_cvt_pk_bf16_f32 %0, %1, %2" : "=v"(wd) : "v"(a[4 * aa + 2 * b2]), "v"(a[4 * aa + 2 * b2 + 1]));
        Wd[aa][b2] = wd;
      }
    bf16x8 pf[2];
#pragma unroll
    for (int ks = 0; ks < 2; ks++) {
      union { unsigned int u[4]; bf16x8 v; } cvt;
#pragma unroll
      for (int b2 = 0; b2 < 2; b2++) {
        unsigned int low_w = Wd[2 * ks][b2];
        unsigned int hi_w  = Wd[2 * ks + 1][b2];
        unsigned int msg = hi ? low_w : hi_w;
        unsigned int rec = __shfl_xor(msg, 32);
        cvt.u[b2]     = hi ? rec : low_w;
        cvt.u[2 + b2] = hi ? hi_w : rec;
      }
      pf[ks] = cvt.v;
    }

    o0 = MFMA32(v0, pf[0], o0);
    o0 = MFMA32(v1, pf[1], o0);
    o1 = MFMA32(v2, pf[0], o1);
    o1 = MFMA32(v3, pf[1], o1);

    kcur0 = kn0; kcur1 = kn1; kcur2 = kn2; kcur3 = kn3;
  }

  const float inv = 1.0f / lrun;
  bf16* Op = O + qrow * HD + h * DK + 4 * hi;
#pragma unroll
  for (int dt = 0; dt < 2; dt++) {
    const f32x16 oo = dt ? o1 : o0;
#pragma unroll
    for (int a2 = 0; a2 < 4; a2++) {
      bf16x4 ob = {(bf16)(oo[4 * a2 + 0] * inv), (bf16)(oo[4 * a2 + 1] * inv),
                   (bf16)(oo[4 * a2 + 2] * inv), (bf16)(oo[4 * a2 + 3] * inv)};
      *(bf16x4*)(Op + dt * 32 + 8 * a2) = ob;
    }
  }
}

extern "C" void kernel_launch(void* const* d_in, const int* in_sizes, int n_in,
                              void* d_out, int out_size, void* d_ws, size_t ws_size,
                              hipStream_t stream) {
  const float* hs = (const float*)d_in[0];
  const float* Wq = (const float*)d_in[1];
  const float* Wk = (const float*)d_in[2];
  const float* Wv = (const float*)d_in[3];
  const float* Wo = (const float*)d_in[4];
  float* out = (float*)d_out;

  char* ws = (char*)d_ws;
  const size_t MB = 1u << 20;
  bf16* Xb = (bf16*)(ws);                 // 16 MB, reused as attention output
  bf16* Qb = (bf16*)(ws + 16 * MB);
  bf16* Kb = (bf16*)(ws + 32 * MB);
  bf16* Vt = (bf16*)(ws + 48 * MB);       // V^T [64 bh][64 d][2048 s]
  bf16* Wtq = (bf16*)(ws + 64 * MB);
  bf16* Wtk = Wtq + 512 * 512;
  bf16* Wtv = Wtk + 512 * 512;
  bf16* Wto = Wtv + 512 * 512;
  float2* ctab = (float2*)(ws + 64 * MB + 4 * 512 * 512 * sizeof(bf16));
  bf16* AO = Xb;

  k_conv<<<dim3(Mrows * DM / (256 * 8)), dim3(256), 0, stream>>>(hs, Xb);
  k_transw4<<<dim3(16, 16, 4), dim3(32, 8), 0, stream>>>(Wq, Wk, Wv, Wo, Wtq, Wtk, Wtv, Wto);
  k_ctab<<<dim3(S * 32 / 256), dim3(256), 0, stream>>>(ctab);
  k_gemm_qkv<<<dim3(1536), dim3(256), 0, stream>>>(Xb, Wtq, Wtk, Wtv, Qb, Kb, Vt, ctab);
  k_attn<<<dim3(NBLK * H * 8), dim3(256), 0, stream>>>(Qb, Kb, Vt, AO);
  k_gemm_out<<<dim3(512), dim3(256), 0, stream>>>(AO, Wto, out);
}

// Round 11
// 119.808 us; speedup vs baseline: 1.0529x; 1.0258x over previous
//
#include <hip/hip_runtime.h>

using bf16 = __bf16;
typedef __bf16 bf16x8 __attribute__((ext_vector_type(8)));
typedef __bf16 bf16x4 __attribute__((ext_vector_type(4)));
typedef float f32x4 __attribute__((ext_vector_type(4)));
typedef float f32x16 __attribute__((ext_vector_type(16)));

#define MFMA16(a, b, c) __builtin_amdgcn_mfma_f32_16x16x32_bf16((a), (b), (c), 0, 0, 0)
#define MFMA32(a, b, c) __builtin_amdgcn_mfma_f32_32x32x16_bf16((a), (b), (c), 0, 0, 0)

constexpr int S = 2048, DM = 512, H = 8, DK = 64, HD = 512;
constexpr int NBLK = 16, BLK = 128;
constexpr int Mrows = 8 * S;  // 16384
constexpr float LOG2E = 1.44269504088896340736f;

__device__ __forceinline__ void gll16(const void* g, void* l) {
  __builtin_amdgcn_global_load_lds((const __attribute__((address_space(1))) unsigned int*)g,
                                   (__attribute__((address_space(3))) unsigned int*)l, 16, 0, 0);
}

// ---------------- fp32 -> bf16 convert (hidden) ----------------
__global__ void k_conv(const float* __restrict__ x, bf16* __restrict__ y) {
  size_t i = ((size_t)blockIdx.x * 256 + threadIdx.x) * 8;
  float4 a = *(const float4*)(x + i);
  float4 b = *(const float4*)(x + i + 4);
  bf16x8 o;
  o[0] = (bf16)a.x; o[1] = (bf16)a.y; o[2] = (bf16)a.z; o[3] = (bf16)a.w;
  o[4] = (bf16)b.x; o[5] = (bf16)b.y; o[6] = (bf16)b.z; o[7] = (bf16)b.w;
  *(bf16x8*)(y + i) = o;
}

// ---------------- weight transpose + convert (all 4 weights, z-indexed) ----------------
__global__ void k_transw4(const float* __restrict__ W0, const float* __restrict__ W1,
                          const float* __restrict__ W2, const float* __restrict__ W3,
                          bf16* __restrict__ D0, bf16* __restrict__ D1,
                          bf16* __restrict__ D2, bf16* __restrict__ D3) {
  const int z = blockIdx.z;
  const float* W = (z == 0) ? W0 : (z == 1) ? W1 : (z == 2) ? W2 : W3;
  bf16* Wt = (z == 0) ? D0 : (z == 1) ? D1 : (z == 2) ? D2 : D3;
  __shared__ float tile[32][33];
  int k0 = blockIdx.x * 32, n0 = blockIdx.y * 32;
  int tx = threadIdx.x, ty = threadIdx.y;  // (32,8)
#pragma unroll
  for (int i = 0; i < 4; i++)
    tile[ty * 4 + i][tx] = W[(size_t)(k0 + ty * 4 + i) * 512 + n0 + tx];
  __syncthreads();
#pragma unroll
  for (int i = 0; i < 4; i++)
    Wt[(size_t)(n0 + ty * 4 + i) * 512 + k0 + tx] = (bf16)tile[tx][ty * 4 + i];
}

// ---------------- RoPE cos/sin table ----------------
__global__ void k_ctab(float2* __restrict__ ctab) {
  int idx = blockIdx.x * 256 + threadIdx.x;  // 65536 entries
  int s = idx >> 5, i = idx & 31;
  float invf = exp2f(-(float)i * (13.287712379549449f / 32.0f));  // 10000^(-i/32)
  float ang = (float)s * invf;
  ctab[idx] = make_float2(cosf(ang), sinf(ang));
}

// ---------------- 128x128x(K=512) bf16 GEMM, 3-stage pipeline + counted vmcnt ----------
// (unchanged from R10)
__global__ __launch_bounds__(256) void k_gemm_qkv(
    const bf16* __restrict__ Xb,
    const bf16* __restrict__ Wtq, const bf16* __restrict__ Wtk, const bf16* __restrict__ Wtv,
    bf16* __restrict__ Qo, bf16* __restrict__ Ko, bf16* __restrict__ Vt,
    const float2* __restrict__ ctab) {
  const int bid = blockIdx.x;
  const int xcd = bid & 7, i = bid >> 3;   // 192 blocks per XCD
  const int mloc = i / 12, zy = i % 12;
  const int z = zy >> 2, y = zy & 3;
  const bf16* Wt = (z == 0) ? Wtq : ((z == 1) ? Wtk : Wtv);
  bf16* dst = (z == 0) ? Qo : Ko;
  const float qscale = (z == 0) ? LOG2E : 1.0f;

  __shared__ __align__(16) char Asm3[3][8192];
  __shared__ __align__(16) char Bsm3[3][8192];

  const int t = threadIdx.x, l = t & 63, wid = t >> 6;
  const int l15 = l & 15, l4 = l >> 4;
  const int wm = wid >> 1, wn = wid & 1;
  const size_t arow0 = (size_t)(xcd * 16 + mloc) * 128;
  const size_t brow0 = (size_t)y * 128;

  f32x4 acc[4][4] = {};
  const int rs = wid * 16 + (l >> 2);          // linear dest row
  const int cs = (l & 3) ^ (l >> 4);           // pre-swizzled source chunk, f(row)=(row>>2)&3

  auto stage = [&](int kt, int b) {
    const int k0 = kt * 32;
    gll16(Xb + (arow0 + rs) * 512 + k0 + cs * 8,      Asm3[b] + wid * 1024);
    gll16(Xb + (arow0 + 64 + rs) * 512 + k0 + cs * 8, Asm3[b] + 4096 + wid * 1024);
    gll16(Wt + (brow0 + rs) * 512 + k0 + cs * 8,      Bsm3[b] + wid * 1024);
    gll16(Wt + (brow0 + 64 + rs) * 512 + k0 + cs * 8, Bsm3[b] + 4096 + wid * 1024);
  };

  stage(0, 0);
  stage(1, 1);
  asm volatile("s_waitcnt vmcnt(4)" ::: "memory");
  __builtin_amdgcn_s_barrier();

  int cur = 0;
  for (int kt = 0; kt < 16; ++kt) {
    if (kt + 2 <= 15) stage(kt + 2, (kt + 2) % 3);
    bf16x8 af[4], bfr[4];
#pragma unroll
    for (int mi = 0; mi < 4; mi++) {
      int row = wm * 64 + mi * 16 + l15;
      af[mi] = *(const bf16x8*)(Asm3[cur] + row * 64 + ((l4 ^ (l15 >> 2)) * 16));
    }
#pragma unroll
    for (int ni = 0; ni < 4; ni++) {
      int row = wn * 64 + ni * 16 + l15;
      bfr[ni] = *(const bf16x8*)(Bsm3[cur] + row * 64 + ((l4 ^ (l15 >> 2)) * 16));
    }
#pragma unroll
    for (int mi = 0; mi < 4; mi++)
#pragma unroll
      for (int ni = 0; ni < 4; ni++)
        acc[mi][ni] = MFMA16(af[mi], bfr[ni], acc[mi][ni]);
    if (kt < 15) {
      if (kt < 14) asm volatile("s_waitcnt vmcnt(4)" ::: "memory");
      else         asm volatile("s_waitcnt vmcnt(0)" ::: "memory");
      __builtin_amdgcn_s_barrier();
    }
    cur = (cur == 2) ? 0 : cur + 1;
  }

  if (z == 2) {
    // write V^T: Vt[(b*H + h)*64 + d][s], pack 4 consecutive s (r dim) per store
    const int b = (int)(arow0 >> 11);
#pragma unroll
    for (int mi = 0; mi < 4; mi++) {
      int scol = (int)(arow0 & 2047) + wm * 64 + mi * 16 + l4 * 4;
#pragma unroll
      for (int ni = 0; ni < 4; ni++) {
        int col = (int)brow0 + wn * 64 + ni * 16 + l15;
        int hh = col >> 6, dd = col & 63;
        bf16x4 pk = {(bf16)acc[mi][ni][0], (bf16)acc[mi][ni][1],
                     (bf16)acc[mi][ni][2], (bf16)acc[mi][ni][3]};
        *(bf16x4*)(Vt + ((size_t)((b * H + hh) * 64 + dd)) * 2048 + scol) = pk;
      }
    }
    return;
  }

#pragma unroll
  for (int mi = 0; mi < 4; mi++) {
#pragma unroll
    for (int r = 0; r < 4; r++) {
      int grow = (int)arow0 + wm * 64 + mi * 16 + l4 * 4 + r;
      size_t rowoff = (size_t)grow * 512 + brow0 + wn * 64;
      int s = grow & (S - 1);
      float2 cs0 = ctab[s * 32 + l15];
      float2 cs1 = ctab[s * 32 + 16 + l15];
#pragma unroll
      for (int ni = 0; ni < 4; ni++) {
        float a = acc[mi][ni][r];
        float b = acc[mi][ni ^ 2][r];
        float2 cc = (ni & 1) ? cs1 : cs0;
        float val = (ni < 2) ? (a * cc.x - b * cc.y) : (a * cc.x + b * cc.y);
        dst[rowoff + ni * 16 + l15] = (bf16)(val * qscale);
      }
    }
  }
}

// ---------------- output projection GEMM (3-stage pipeline, L2 swizzle) -> fp32 --------
// (unchanged from R10)
__global__ __launch_bounds__(256) void k_gemm_out(
    const bf16* __restrict__ A, const bf16* __restrict__ Wt, float* __restrict__ out) {
  const int bid = blockIdx.x;
  const int xcd = bid & 7, i = bid >> 3;  // 64 per XCD: 16 m x 4 y
  __shared__ __align__(16) char Asm3[3][8192];
  __shared__ __align__(16) char Bsm3[3][8192];

  const int t = threadIdx.x, l = t & 63, wid = t >> 6;
  const int l15 = l & 15, l4 = l >> 4;
  const int wm = wid >> 1, wn = wid & 1;
  const size_t arow0 = (size_t)(xcd * 16 + (i >> 2)) * 128;
  const size_t brow0 = (size_t)(i & 3) * 128;

  f32x4 acc[4][4] = {};
  const int rs = wid * 16 + (l >> 2);
  const int cs = (l & 3) ^ (l >> 4);

  auto stage = [&](int kt, int b) {
    const int k0 = kt * 32;
    gll16(A + (arow0 + rs) * 512 + k0 + cs * 8,       Asm3[b] + wid * 1024);
    gll16(A + (arow0 + 64 + rs) * 512 + k0 + cs * 8,  Asm3[b] + 4096 + wid * 1024);
    gll16(Wt + (brow0 + rs) * 512 + k0 + cs * 8,      Bsm3[b] + wid * 1024);
    gll16(Wt + (brow0 + 64 + rs) * 512 + k0 + cs * 8, Bsm3[b] + 4096 + wid * 1024);
  };

  stage(0, 0);
  stage(1, 1);
  asm volatile("s_waitcnt vmcnt(4)" ::: "memory");
  __builtin_amdgcn_s_barrier();

  int cur = 0;
  for (int kt = 0; kt < 16; ++kt) {
    if (kt + 2 <= 15) stage(kt + 2, (kt + 2) % 3);
    bf16x8 af[4], bfr[4];
#pragma unroll
    for (int mi = 0; mi < 4; mi++) {
      int row = wm * 64 + mi * 16 + l15;
      af[mi] = *(const bf16x8*)(Asm3[cur] + row * 64 + ((l4 ^ (l15 >> 2)) * 16));
    }
#pragma unroll
    for (int ni = 0; ni < 4; ni++) {
      int row = wn * 64 + ni * 16 + l15;
      bfr[ni] = *(const bf16x8*)(Bsm3[cur] + row * 64 + ((l4 ^ (l15 >> 2)) * 16));
    }
#pragma unroll
    for (int mi = 0; mi < 4; mi++)
#pragma unroll
      for (int ni = 0; ni < 4; ni++)
        acc[mi][ni] = MFMA16(af[mi], bfr[ni], acc[mi][ni]);
    if (kt < 15) {
      if (kt < 14) asm volatile("s_waitcnt vmcnt(4)" ::: "memory");
      else         asm volatile("s_waitcnt vmcnt(0)" ::: "memory");
      __builtin_amdgcn_s_barrier();
    }
    cur = (cur == 2) ? 0 : cur + 1;
  }

#pragma unroll
  for (int mi = 0; mi < 4; mi++)
#pragma unroll
    for (int r = 0; r < 4; r++) {
      int grow = (int)arow0 + wm * 64 + mi * 16 + l4 * 4 + r;
      size_t rowoff = (size_t)grow * 512 + brow0 + wn * 64;
#pragma unroll
      for (int ni = 0; ni < 4; ni++)
        out[rowoff + ni * 16 + l15] = acc[mi][ni][r];
    }
}

// ---------------- block-banded flash attention: R5 paired-chunk form + s_setprio ------
// 1024 blocks (XCD-swizzled), 256 thr = 4 waves x 32 q-rows. 5 softmax steps of 64/32 keys.
// Operands direct from global (L2-resident); P^T built in-register (cvt_pk + shfl_xor 32).
// Q pre-scaled by LOG2E (exp2 domain). Defer-max: skip rescale unless max grows by >8.
__global__ __launch_bounds__(256, 4) void k_attn(
    const bf16* __restrict__ Q, const bf16* __restrict__ K, const bf16* __restrict__ Vt,
    bf16* __restrict__ O) {
  // XCD swizzle: XCD x owns logical ids [x*128, x*128+128) = one full batch
  const int bid = blockIdx.x;
  const int swz = (bid & 7) * 128 + (bid >> 3);
  const int nb = swz & 15, h = (swz >> 4) & 7, bb = swz >> 7;
  const int t = threadIdx.x, l = t & 63, w = t >> 6;
  const int q31 = l & 31, hi = l >> 5;

  const int bh = bb * H + h;
  const size_t qrow = (size_t)bb * S + nb * BLK + w * 32 + q31;

  // Q B-frags: col q = l&31, k(dk) = ks*16 + hi*8 + j
  const bf16* Qp = Q + qrow * HD + h * DK + hi * 8;
  bf16x8 qb[4];
#pragma unroll
  for (int ks = 0; ks < 4; ks++) qb[ks] = *(const bf16x8*)(Qp + ks * 16);

  f32x16 o0 = {}, o1 = {};  // O^T[d][q]: q = l&31, d = dt*32 + (rg&3)+8*(rg>>2)+4*hi
  float mrun = -3e38f, lrun = 0.f;

  const bf16* Kbase = K + (size_t)bb * S * HD + h * DK + hi * 8;
  const bf16* Vbase = Vt + ((size_t)bh * 64 + q31) * 2048 + hi * 8;
  const int s0 = nb * BLK + w * 32 - 128;  // window start (chunk 0), 9 chunks of 32

  // PV helper: convert 16 in-lane p's (one 32-key chunk) to P^T B-frags and MFMA with V^T.
  auto pv = [&](const f32x16& p, int kgc) {
    unsigned int Wd[4][2];
#pragma unroll
    for (int a = 0; a < 4; a++)
#pragma unroll
      for (int b2 = 0; b2 < 2; b2++) {
        unsigned int wd;
        asm("v_cvt_pk_bf16_f32 %0, %1, %2" : "=v"(wd) : "v"(p[4 * a + 2 * b2]), "v"(p[4 * a + 2 * b2 + 1]));
        Wd[a][b2] = wd;
      }
    bf16x8 pf[2];
#pragma unroll
    for (int ks = 0; ks < 2; ks++) {
      union { unsigned int u[4]; bf16x8 v; } cvt;
#pragma unroll
      for (int b2 = 0; b2 < 2; b2++) {
        unsigned int low_w = Wd[2 * ks][b2];      // keys 16ks + 4hi + 2b
        unsigned int hi_w  = Wd[2 * ks + 1][b2];  // keys 16ks + 8 + 4hi + 2b
        unsigned int msg = hi ? low_w : hi_w;     // send what the other half needs
        unsigned int rec = __shfl_xor(msg, 32);
        cvt.u[b2]     = hi ? rec : low_w;         // keys 16ks + 8hi + 2b
        cvt.u[2 + b2] = hi ? hi_w : rec;          // keys 16ks + 8hi + 4 + 2b
      }
      pf[ks] = cvt.v;
    }
    const bf16* Vp = Vbase + kgc;
    __builtin_amdgcn_s_setprio(1);
    o0 = MFMA32(*(const bf16x8*)(Vp), pf[0], o0);
    o0 = MFMA32(*(const bf16x8*)(Vp + 16), pf[1], o0);
    o1 = MFMA32(*(const bf16x8*)(Vp + 32 * 2048), pf[0], o1);
    o1 = MFMA32(*(const bf16x8*)(Vp + 32 * 2048 + 16), pf[1], o1);
    __builtin_amdgcn_s_setprio(0);
  };

#pragma unroll
  for (int st = 0; st < 5; ++st) {
    const bool has2 = (st < 4);
    const int c0 = st * 2, c1 = c0 + 1;
    const int kg0 = s0 + c0 * 32, kg1 = s0 + c1 * 32;
    const int kc0 = kg0 < 0 ? 0 : (kg0 > S - 32 ? S - 32 : kg0);
    const int kc1 = kg1 < 0 ? 0 : (kg1 > S - 32 ? S - 32 : kg1);

    f32x16 a0 = {}, a1 = {};
    {
      const bf16* Kp = Kbase + (size_t)(kc0 + q31) * HD;
      __builtin_amdgcn_s_setprio(1);
      a0 = MFMA32(*(const bf16x8*)(Kp),      qb[0], a0);
      a0 = MFMA32(*(const bf16x8*)(Kp + 16), qb[1], a0);
      a0 = MFMA32(*(const bf16x8*)(Kp + 32), qb[2], a0);
      a0 = MFMA32(*(const bf16x8*)(Kp + 48), qb[3], a0);
      __builtin_amdgcn_s_setprio(0);
    }
    if (has2) {
      const bf16* Kp = Kbase + (size_t)(kc1 + q31) * HD;
      __builtin_amdgcn_s_setprio(1);
      a1 = MFMA32(*(const bf16x8*)(Kp),      qb[0], a1);
      a1 = MFMA32(*(const bf16x8*)(Kp + 16), qb[1], a1);
      a1 = MFMA32(*(const bf16x8*)(Kp + 32), qb[2], a1);
      a1 = MFMA32(*(const bf16x8*)(Kp + 48), qb[3], a1);
      __builtin_amdgcn_s_setprio(0);
    }

    // masks (c0==0 / c0==8 triangles fold at compile time after unroll)
    if (kg0 != kc0) {
#pragma unroll
      for (int rg = 0; rg < 16; rg++) a0[rg] = -1e30f;
    } else if (c0 == 0) {
#pragma unroll
      for (int rg = 0; rg < 16; rg++) {
        int kk = (rg & 3) + 8 * (rg >> 2) + 4 * hi;
        if (kk < q31) a0[rg] = -1e30f;  // valid iff kk >= q
      }
    } else if (c0 == 8) {
#pragma unroll
      for (int rg = 0; rg < 16; rg++) {
        int kk = (rg & 3) + 8 * (rg >> 2) + 4 * hi;
        if (kk > q31) a0[rg] = -1e30f;  // valid iff kk <= q
      }
    }
    if (has2 && kg1 != kc1) {
#pragma unroll
      for (int rg = 0; rg < 16; rg++) a1[rg] = -1e30f;
    }

    // step max (tree) + half-wave combine
    f32x16 mx = a0;
    if (has2) {
#pragma unroll
      for (int rg = 0; rg < 16; rg++) mx[rg] = fmaxf(mx[rg], a1[rg]);
    }
#pragma unroll
    for (int sl = 8; sl >= 1; sl >>= 1)
#pragma unroll
      for (int i2 = 0; i2 < sl; i2++) mx[i2] = fmaxf(mx[i2], mx[i2 + sl]);
    const float pm = fmaxf(mx[0], __shfl_xor(mx[0], 32));

    // defer-max: rescale only if max grew by > 8 (wave-uniform vote)
    if (!__all(pm - mrun <= 8.0f)) {
      const float mnew = fmaxf(mrun, pm);
      const float alpha = exp2f(mrun - mnew);
      lrun *= alpha;
#pragma unroll
      for (int rg = 0; rg < 16; rg++) { o0[rg] *= alpha; o1[rg] *= alpha; }
      mrun = mnew;
    }

    float rsum = 0.f;
#pragma unroll
    for (int rg = 0; rg < 16; rg++) { a0[rg] = exp2f(a0[rg] - mrun); rsum += a0[rg]; }
    if (has2) {
#pragma unroll
      for (int rg = 0; rg < 16; rg++) { a1[rg] = exp2f(a1[rg] - mrun); rsum += a1[rg]; }
    }
    rsum += __shfl_xor(rsum, 32);
    lrun += rsum;

    pv(a0, kc0);
    if (has2) pv(a1, kc1);
  }

  const float inv = 1.0f / lrun;
  bf16* Op = O + qrow * HD + h * DK + 4 * hi;
#pragma unroll
  for (int dt = 0; dt < 2; dt++) {
    const f32x16 oo = dt ? o1 : o0;
#pragma unroll
    for (int a = 0; a < 4; a++) {
      bf16x4 ob = {(bf16)(oo[4 * a + 0] * inv), (bf16)(oo[4 * a + 1] * inv),
                   (bf16)(oo[4 * a + 2] * inv), (bf16)(oo[4 * a + 3] * inv)};
      *(bf16x4*)(Op + dt * 32 + 8 * a) = ob;  // d = dt*32 + 8a + 4hi + (0..3)
    }
  }
}

extern "C" void kernel_launch(void* const* d_in, const int* in_sizes, int n_in,
                              void* d_out, int out_size, void* d_ws, size_t ws_size,
                              hipStream_t stream) {
  const float* hs = (const float*)d_in[0];
  const float* Wq = (const float*)d_in[1];
  const float* Wk = (const float*)d_in[2];
  const float* Wv = (const float*)d_in[3];
  const float* Wo = (const float*)d_in[4];
  float* out = (float*)d_out;

  char* ws = (char*)d_ws;
  const size_t MB = 1u << 20;
  bf16* Xb = (bf16*)(ws);                 // 16 MB, reused as attention output
  bf16* Qb = (bf16*)(ws + 16 * MB);
  bf16* Kb = (bf16*)(ws + 32 * MB);
  bf16* Vt = (bf16*)(ws + 48 * MB);       // V^T [64 bh][64 d][2048 s]
  bf16* Wtq = (bf16*)(ws + 64 * MB);
  bf16* Wtk = Wtq + 512 * 512;
  bf16* Wtv = Wtk + 512 * 512;
  bf16* Wto = Wtv + 512 * 512;
  float2* ctab = (float2*)(ws + 64 * MB + 4 * 512 * 512 * sizeof(bf16));
  bf16* AO = Xb;

  k_conv<<<dim3(Mrows * DM / (256 * 8)), dim3(256), 0, stream>>>(hs, Xb);
  k_transw4<<<dim3(16, 16, 4), dim3(32, 8), 0, stream>>>(Wq, Wk, Wv, Wo, Wtq, Wtk, Wtv, Wto);
  k_ctab<<<dim3(S * 32 / 256), dim3(256), 0, stream>>>(ctab);
  k_gemm_qkv<<<dim3(1536), dim3(256), 0, stream>>>(Xb, Wtq, Wtk, Wtv, Qb, Kb, Vt, ctab);
  k_attn<<<dim3(NBLK * H * 8), dim3(256), 0, stream>>>(Qb, Kb, Vt, AO);
  k_gemm_out<<<dim3(512), dim3(256), 0, stream>>>(AO, Wto, out);
}

// Round 12
// 110.306 us; speedup vs baseline: 1.1436x; 1.0861x over previous
//
#include <hip/hip_runtime.h>

using bf16 = __bf16;
typedef __bf16 bf16x8 __attribute__((ext_vector_type(8)));
typedef __bf16 bf16x4 __attribute__((ext_vector_type(4)));
typedef float f32x4 __attribute__((ext_vector_type(4)));
typedef float f32x16 __attribute__((ext_vector_type(16)));

#define MFMA16(a, b, c) __builtin_amdgcn_mfma_f32_16x16x32_bf16((a), (b), (c), 0, 0, 0)
#define MFMA32(a, b, c) __builtin_amdgcn_mfma_f32_32x32x16_bf16((a), (b), (c), 0, 0, 0)

constexpr int S = 2048, DM = 512, H = 8, DK = 64, HD = 512;
constexpr int NBLK = 16, BLK = 128;
constexpr int Mrows = 8 * S;  // 16384
constexpr float LOG2E = 1.44269504088896340736f;

__device__ __forceinline__ void gll16(const void* g, void* l) {
  __builtin_amdgcn_global_load_lds((const __attribute__((address_space(1))) unsigned int*)g,
                                   (__attribute__((address_space(3))) unsigned int*)l, 16, 0, 0);
}

// ---------------- fp32 -> bf16 convert (hidden) ----------------
__global__ void k_conv(const float* __restrict__ x, bf16* __restrict__ y) {
  size_t i = ((size_t)blockIdx.x * 256 + threadIdx.x) * 8;
  float4 a = *(const float4*)(x + i);
  float4 b = *(const float4*)(x + i + 4);
  bf16x8 o;
  o[0] = (bf16)a.x; o[1] = (bf16)a.y; o[2] = (bf16)a.z; o[3] = (bf16)a.w;
  o[4] = (bf16)b.x; o[5] = (bf16)b.y; o[6] = (bf16)b.z; o[7] = (bf16)b.w;
  *(bf16x8*)(y + i) = o;
}

// ---------------- weight transpose + convert (all 4 weights, z-indexed) ----------------
__global__ void k_transw4(const float* __restrict__ W0, const float* __restrict__ W1,
                          const float* __restrict__ W2, const float* __restrict__ W3,
                          bf16* __restrict__ D0, bf16* __restrict__ D1,
                          bf16* __restrict__ D2, bf16* __restrict__ D3) {
  const int z = blockIdx.z;
  const float* W = (z == 0) ? W0 : (z == 1) ? W1 : (z == 2) ? W2 : W3;
  bf16* Wt = (z == 0) ? D0 : (z == 1) ? D1 : (z == 2) ? D2 : D3;
  __shared__ float tile[32][33];
  int k0 = blockIdx.x * 32, n0 = blockIdx.y * 32;
  int tx = threadIdx.x, ty = threadIdx.y;  // (32,8)
#pragma unroll
  for (int i = 0; i < 4; i++)
    tile[ty * 4 + i][tx] = W[(size_t)(k0 + ty * 4 + i) * 512 + n0 + tx];
  __syncthreads();
#pragma unroll
  for (int i = 0; i < 4; i++)
    Wt[(size_t)(n0 + ty * 4 + i) * 512 + k0 + tx] = (bf16)tile[tx][ty * 4 + i];
}

// ---------------- RoPE cos/sin table ----------------
__global__ void k_ctab(float2* __restrict__ ctab) {
  int idx = blockIdx.x * 256 + threadIdx.x;  // 65536 entries
  int s = idx >> 5, i = idx & 31;
  float invf = exp2f(-(float)i * (13.287712379549449f / 32.0f));  // 10000^(-i/32)
  float ang = (float)s * invf;
  ctab[idx] = make_float2(cosf(ang), sinf(ang));
}

// ---------------- 128x128x(K=512) bf16 GEMM, 3-stage pipeline + counted vmcnt ----------
// LDS swizzle f(row)=(row>>1)&3 (conflict-free under 8-lane phases).
// z=0: Q (rope, *LOG2E) -> Qo flat [row][512].
// z=1: K (rope) -> K' [bh][dk/16][s 2048][16]  (attn-coalesced)
// z=2: V        -> VtP [bh][s/16][d 64][16]    (attn-coalesced)
__global__ __launch_bounds__(256) void k_gemm_qkv(
    const bf16* __restrict__ Xb,
    const bf16* __restrict__ Wtq, const bf16* __restrict__ Wtk, const bf16* __restrict__ Wtv,
    bf16* __restrict__ Qo, bf16* __restrict__ Ko, bf16* __restrict__ Vt,
    const float2* __restrict__ ctab) {
  const int bid = blockIdx.x;
  const int xcd = bid & 7, i = bid >> 3;   // 192 blocks per XCD
  const int mloc = i / 12, zy = i % 12;
  const int z = zy >> 2, y = zy & 3;
  const bf16* Wt = (z == 0) ? Wtq : ((z == 1) ? Wtk : Wtv);
  const float qscale = (z == 0) ? LOG2E : 1.0f;

  __shared__ __align__(16) char Asm3[3][8192];
  __shared__ __align__(16) char Bsm3[3][8192];

  const int t = threadIdx.x, l = t & 63, wid = t >> 6;
  const int l15 = l & 15, l4 = l >> 4;
  const int wm = wid >> 1, wn = wid & 1;
  const size_t arow0 = (size_t)(xcd * 16 + mloc) * 128;
  const size_t brow0 = (size_t)y * 128;

  f32x4 acc[4][4] = {};
  const int rs = wid * 16 + (l >> 2);          // linear dest row
  const int cs = (l & 3) ^ ((l >> 3) & 3);     // pre-swizzled source chunk, f(row)=(row>>1)&3

  auto stage = [&](int kt, int b) {
    const int k0 = kt * 32;
    gll16(Xb + (arow0 + rs) * 512 + k0 + cs * 8,      Asm3[b] + wid * 1024);
    gll16(Xb + (arow0 + 64 + rs) * 512 + k0 + cs * 8, Asm3[b] + 4096 + wid * 1024);
    gll16(Wt + (brow0 + rs) * 512 + k0 + cs * 8,      Bsm3[b] + wid * 1024);
    gll16(Wt + (brow0 + 64 + rs) * 512 + k0 + cs * 8, Bsm3[b] + 4096 + wid * 1024);
  };

  stage(0, 0);
  stage(1, 1);
  asm volatile("s_waitcnt vmcnt(4)" ::: "memory");
  __builtin_amdgcn_s_barrier();

  int cur = 0;
  for (int kt = 0; kt < 16; ++kt) {
    if (kt + 2 <= 15) stage(kt + 2, (kt + 2) % 3);
    bf16x8 af[4], bfr[4];
#pragma unroll
    for (int mi = 0; mi < 4; mi++) {
      int row = wm * 64 + mi * 16 + l15;
      af[mi] = *(const bf16x8*)(Asm3[cur] + row * 64 + ((l4 ^ ((l15 >> 1) & 3)) * 16));
    }
#pragma unroll
    for (int ni = 0; ni < 4; ni++) {
      int row = wn * 64 + ni * 16 + l15;
      bfr[ni] = *(const bf16x8*)(Bsm3[cur] + row * 64 + ((l4 ^ ((l15 >> 1) & 3)) * 16));
    }
#pragma unroll
    for (int mi = 0; mi < 4; mi++)
#pragma unroll
      for (int ni = 0; ni < 4; ni++)
        acc[mi][ni] = MFMA16(af[mi], bfr[ni], acc[mi][ni]);
    if (kt < 15) {
      if (kt < 14) asm volatile("s_waitcnt vmcnt(4)" ::: "memory");
      else         asm volatile("s_waitcnt vmcnt(0)" ::: "memory");
      __builtin_amdgcn_s_barrier();
    }
    cur = (cur == 2) ? 0 : cur + 1;
  }

  const int b = (int)(arow0 >> 11);
  const int hh = (int)(brow0 >> 6) + wn;  // head for this wave's column half

  if (z == 2) {
    // VtP[bh][s/16][d][16]: bf16x4 over s-within-sliver
    const int sbase = (int)(arow0 & 2047) + wm * 64;
#pragma unroll
    for (int mi = 0; mi < 4; mi++) {
      int sg = (sbase + mi * 16) >> 4;
      int slo = l4 * 4;
#pragma unroll
      for (int ni = 0; ni < 4; ni++) {
        int dd = ni * 16 + l15;
        bf16x4 pk = {(bf16)acc[mi][ni][0], (bf16)acc[mi][ni][1],
                     (bf16)acc[mi][ni][2], (bf16)acc[mi][ni][3]};
        *(bf16x4*)(Vt + (((size_t)(b * H + hh) * 128 + sg) * 64 + dd) * 16 + slo) = pk;
      }
    }
    return;
  }

#pragma unroll
  for (int mi = 0; mi < 4; mi++) {
#pragma unroll
    for (int r = 0; r < 4; r++) {
      int grow = (int)arow0 + wm * 64 + mi * 16 + l4 * 4 + r;
      int s = grow & (S - 1);
      float2 cs0 = ctab[s * 32 + l15];
      float2 cs1 = ctab[s * 32 + 16 + l15];
#pragma unroll
      for (int ni = 0; ni < 4; ni++) {
        float a = acc[mi][ni][r];
        float b2 = acc[mi][ni ^ 2][r];
        float2 cc = (ni & 1) ? cs1 : cs0;
        float val = (ni < 2) ? (a * cc.x - b2 * cc.y) : (a * cc.x + b2 * cc.y);
        if (z == 0) {
          Qo[(size_t)grow * 512 + brow0 + wn * 64 + ni * 16 + l15] = (bf16)(val * qscale);
        } else {
          // K'[bh][ni][s][16]
          Ko[(((size_t)(b * H + hh) * 4 + ni) * 2048 + s) * 16 + l15] = (bf16)val;
        }
      }
    }
  }
}

// ---------------- output projection GEMM (3-stage pipeline, L2 swizzle) -> fp32 --------
__global__ __launch_bounds__(256) void k_gemm_out(
    const bf16* __restrict__ A, const bf16* __restrict__ Wt, float* __restrict__ out) {
  const int bid = blockIdx.x;
  const int xcd = bid & 7, i = bid >> 3;  // 64 per XCD: 16 m x 4 y
  __shared__ __align__(16) char Asm3[3][8192];
  __shared__ __align__(16) char Bsm3[3][8192];

  const int t = threadIdx.x, l = t & 63, wid = t >> 6;
  const int l15 = l & 15, l4 = l >> 4;
  const int wm = wid >> 1, wn = wid & 1;
  const size_t arow0 = (size_t)(xcd * 16 + (i >> 2)) * 128;
  const size_t brow0 = (size_t)(i & 3) * 128;

  f32x4 acc[4][4] = {};
  const int rs = wid * 16 + (l >> 2);
  const int cs = (l & 3) ^ ((l >> 3) & 3);

  auto stage = [&](int kt, int b) {
    const int k0 = kt * 32;
    gll16(A + (arow0 + rs) * 512 + k0 + cs * 8,       Asm3[b] + wid * 1024);
    gll16(A + (arow0 + 64 + rs) * 512 + k0 + cs * 8,  Asm3[b] + 4096 + wid * 1024);
    gll16(Wt + (brow0 + rs) * 512 + k0 + cs * 8,      Bsm3[b] + wid * 1024);
    gll16(Wt + (brow0 + 64 + rs) * 512 + k0 + cs * 8, Bsm3[b] + 4096 + wid * 1024);
  };

  stage(0, 0);
  stage(1, 1);
  asm volatile("s_waitcnt vmcnt(4)" ::: "memory");
  __builtin_amdgcn_s_barrier();

  int cur = 0;
  for (int kt = 0; kt < 16; ++kt) {
    if (kt + 2 <= 15) stage(kt + 2, (kt + 2) % 3);
    bf16x8 af[4], bfr[4];
#pragma unroll
    for (int mi = 0; mi < 4; mi++) {
      int row = wm * 64 + mi * 16 + l15;
      af[mi] = *(const bf16x8*)(Asm3[cur] + row * 64 + ((l4 ^ ((l15 >> 1) & 3)) * 16));
    }
#pragma unroll
    for (int ni = 0; ni < 4; ni++) {
      int row = wn * 64 + ni * 16 + l15;
      bfr[ni] = *(const bf16x8*)(Bsm3[cur] + row * 64 + ((l4 ^ ((l15 >> 1) & 3)) * 16));
    }
#pragma unroll
    for (int mi = 0; mi < 4; mi++)
#pragma unroll
      for (int ni = 0; ni < 4; ni++)
        acc[mi][ni] = MFMA16(af[mi], bfr[ni], acc[mi][ni]);
    if (kt < 15) {
      if (kt < 14) asm volatile("s_waitcnt vmcnt(4)" ::: "memory");
      else         asm volatile("s_waitcnt vmcnt(0)" ::: "memory");
      __builtin_amdgcn_s_barrier();
    }
    cur = (cur == 2) ? 0 : cur + 1;
  }

#pragma unroll
  for (int mi = 0; mi < 4; mi++)
#pragma unroll
    for (int r = 0; r < 4; r++) {
      int grow = (int)arow0 + wm * 64 + mi * 16 + l4 * 4 + r;
      size_t rowoff = (size_t)grow * 512 + brow0 + wn * 64;
#pragma unroll
      for (int ni = 0; ni < 4; ni++)
        out[rowoff + ni * 16 + l15] = acc[mi][ni][r];
    }
}

// ---------------- block-banded flash attention: coalesced layouts + setprio ------
// 1024 blocks (XCD-swizzled), 256 thr = 4 waves x 32 q-rows. 5 softmax steps of 64/32 keys.
// K'[bh][ks][s][16] and VtP[bh][s/16][d][16]: every frag load = contiguous 1KB per wave.
// P^T built in-register (cvt_pk + shfl_xor 32). Q pre-scaled by LOG2E. Defer-max THR=8.
__global__ __launch_bounds__(256, 4) void k_attn(
    const bf16* __restrict__ Q, const bf16* __restrict__ Kp, const bf16* __restrict__ VtP,
    bf16* __restrict__ O) {
  const int bid = blockIdx.x;
  const int swz = (bid & 7) * 128 + (bid >> 3);
  const int nb = swz & 15, h = (swz >> 4) & 7, bb = swz >> 7;
  const int t = threadIdx.x, l = t & 63, w = t >> 6;
  const int q31 = l & 31, hi = l >> 5;

  const int bh = bb * H + h;
  const size_t qrow = (size_t)bb * S + nb * BLK + w * 32 + q31;

  // Q B-frags: col q = l&31, k(dk) = ks*16 + hi*8 + j  (flat layout; once per block)
  const bf16* Qp = Q + qrow * HD + h * DK + hi * 8;
  bf16x8 qb[4];
#pragma unroll
  for (int ks = 0; ks < 4; ks++) qb[ks] = *(const bf16x8*)(Qp + ks * 16);

  f32x16 o0 = {}, o1 = {};  // O^T[d][q]: q = l&31, d = dt*32 + (rg&3)+8*(rg>>2)+4*hi
  float mrun = -3e38f, lrun = 0.f;

  const bf16* Kbh = Kp + (size_t)bh * 131072;            // 4 planes x 2048 x 16
  const bf16* Vbh = VtP + (size_t)bh * 131072;           // 128 slivers x 64 d x 16
  const int s0 = nb * BLK + w * 32 - 128;  // window start (chunk 0), 9 chunks of 32

  // PV helper: convert 16 in-lane p's (one 32-key chunk) to P^T B-frags and MFMA with V^T.
  auto pv = [&](const f32x16& p, int kgc) {
    unsigned int Wd[4][2];
#pragma unroll
    for (int a = 0; a < 4; a++)
#pragma unroll
      for (int b2 = 0; b2 < 2; b2++) {
        unsigned int wd;
        asm("v_cvt_pk_bf16_f32 %0, %1, %2" : "=v"(wd) : "v"(p[4 * a + 2 * b2]), "v"(p[4 * a + 2 * b2 + 1]));
        Wd[a][b2] = wd;
      }
    bf16x8 pf[2];
#pragma unroll
    for (int ks = 0; ks < 2; ks++) {
      union { unsigned int u[4]; bf16x8 v; } cvt;
#pragma unroll
      for (int b2 = 0; b2 < 2; b2++) {
        unsigned int low_w = Wd[2 * ks][b2];      // keys 16ks + 4hi + 2b
        unsigned int hi_w  = Wd[2 * ks + 1][b2];  // keys 16ks + 8 + 4hi + 2b
        unsigned int msg = hi ? low_w : hi_w;     // send what the other half needs
        unsigned int rec = __shfl_xor(msg, 32);
        cvt.u[b2]     = hi ? rec : low_w;         // keys 16ks + 8hi + 2b
        cvt.u[2 + b2] = hi ? hi_w : rec;          // keys 16ks + 8hi + 4 + 2b
      }
      pf[ks] = cvt.v;
    }
    const bf16* Vs = Vbh + (size_t)(kgc >> 4) * 1024 + q31 * 16 + hi * 8;
    __builtin_amdgcn_s_setprio(1);
    o0 = MFMA32(*(const bf16x8*)(Vs),               pf[0], o0);
    o0 = MFMA32(*(const bf16x8*)(Vs + 1024),        pf[1], o0);
    o1 = MFMA32(*(const bf16x8*)(Vs + 512),         pf[0], o1);
    o1 = MFMA32(*(const bf16x8*)(Vs + 1024 + 512),  pf[1], o1);
    __builtin_amdgcn_s_setprio(0);
  };

#pragma unroll
  for (int st = 0; st < 5; ++st) {
    const bool has2 = (st < 4);
    const int c0 = st * 2, c1 = c0 + 1;
    const int kg0 = s0 + c0 * 32, kg1 = s0 + c1 * 32;
    const int kc0 = kg0 < 0 ? 0 : (kg0 > S - 32 ? S - 32 : kg0);
    const int kc1 = kg1 < 0 ? 0 : (kg1 > S - 32 ? S - 32 : kg1);

    f32x16 a0 = {}, a1 = {};
    {
      const bf16* Kl = Kbh + (size_t)(kc0 + q31) * 16 + hi * 8;
      __builtin_amdgcn_s_setprio(1);
      a0 = MFMA32(*(const bf16x8*)(Kl),          qb[0], a0);
      a0 = MFMA32(*(const bf16x8*)(Kl + 32768),  qb[1], a0);
      a0 = MFMA32(*(const bf16x8*)(Kl + 65536),  qb[2], a0);
      a0 = MFMA32(*(const bf16x8*)(Kl + 98304),  qb[3], a0);
      __builtin_amdgcn_s_setprio(0);
    }
    if (has2) {
      const bf16* Kl = Kbh + (size_t)(kc1 + q31) * 16 + hi * 8;
      __builtin_amdgcn_s_setprio(1);
      a1 = MFMA32(*(const bf16x8*)(Kl),          qb[0], a1);
      a1 = MFMA32(*(const bf16x8*)(Kl + 32768),  qb[1], a1);
      a1 = MFMA32(*(const bf16x8*)(Kl + 65536),  qb[2], a1);
      a1 = MFMA32(*(const bf16x8*)(Kl + 98304),  qb[3], a1);
      __builtin_amdgcn_s_setprio(0);
    }

    // masks (c0==0 / c0==8 triangles fold at compile time after unroll)
    if (kg0 != kc0) {
#pragma unroll
      for (int rg = 0; rg < 16; rg++) a0[rg] = -1e30f;
    } else if (c0 == 0) {
#pragma unroll
      for (int rg = 0; rg < 16; rg++) {
        int kk = (rg & 3) + 8 * (rg >> 2) + 4 * hi;
        if (kk < q31) a0[rg] = -1e30f;  // valid iff kk >= q
      }
    } else if (c0 == 8) {
#pragma unroll
      for (int rg = 0; rg < 16; rg++) {
        int kk = (rg & 3) + 8 * (rg >> 2) + 4 * hi;
        if (kk > q31) a0[rg] = -1e30f;  // valid iff kk <= q
      }
    }
    if (has2 && kg1 != kc1) {
#pragma unroll
      for (int rg = 0; rg < 16; rg++) a1[rg] = -1e30f;
    }

    // step max (tree) + half-wave combine
    f32x16 mx = a0;
    if (has2) {
#pragma unroll
      for (int rg = 0; rg < 16; rg++) mx[rg] = fmaxf(mx[rg], a1[rg]);
    }
#pragma unroll
    for (int sl = 8; sl >= 1; sl >>= 1)
#pragma unroll
      for (int i2 = 0; i2 < sl; i2++) mx[i2] = fmaxf(mx[i2], mx[i2 + sl]);
    const float pm = fmaxf(mx[0], __shfl_xor(mx[0], 32));

    // defer-max: rescale only if max grew by > 8 (wave-uniform vote)
    if (!__all(pm - mrun <= 8.0f)) {
      const float mnew = fmaxf(mrun, pm);
      const float alpha = exp2f(mrun - mnew);
      lrun *= alpha;
#pragma unroll
      for (int rg = 0; rg < 16; rg++) { o0[rg] *= alpha; o1[rg] *= alpha; }
      mrun = mnew;
    }

    float rsum = 0.f;
#pragma unroll
    for (int rg = 0; rg < 16; rg++) { a0[rg] = exp2f(a0[rg] - mrun); rsum += a0[rg]; }
    if (has2) {
#pragma unroll
      for (int rg = 0; rg < 16; rg++) { a1[rg] = exp2f(a1[rg] - mrun); rsum += a1[rg]; }
    }
    rsum += __shfl_xor(rsum, 32);
    lrun += rsum;

    pv(a0, kc0);
    if (has2) pv(a1, kc1);
  }

  const float inv = 1.0f / lrun;
  bf16* Op = O + qrow * HD + h * DK + 4 * hi;
#pragma unroll
  for (int dt = 0; dt < 2; dt++) {
    const f32x16 oo = dt ? o1 : o0;
#pragma unroll
    for (int a = 0; a < 4; a++) {
      bf16x4 ob = {(bf16)(oo[4 * a + 0] * inv), (bf16)(oo[4 * a + 1] * inv),
                   (bf16)(oo[4 * a + 2] * inv), (bf16)(oo[4 * a + 3] * inv)};
      *(bf16x4*)(Op + dt * 32 + 8 * a) = ob;  // d = dt*32 + 8a + 4hi + (0..3)
    }
  }
}

extern "C" void kernel_launch(void* const* d_in, const int* in_sizes, int n_in,
                              void* d_out, int out_size, void* d_ws, size_t ws_size,
                              hipStream_t stream) {
  const float* hs = (const float*)d_in[0];
  const float* Wq = (const float*)d_in[1];
  const float* Wk = (const float*)d_in[2];
  const float* Wv = (const float*)d_in[3];
  const float* Wo = (const float*)d_in[4];
  float* out = (float*)d_out;

  char* ws = (char*)d_ws;
  const size_t MB = 1u << 20;
  bf16* Xb = (bf16*)(ws);                 // 16 MB, reused as attention output
  bf16* Qb = (bf16*)(ws + 16 * MB);
  bf16* Kb = (bf16*)(ws + 32 * MB);       // K' [64 bh][4][2048][16]
  bf16* Vt = (bf16*)(ws + 48 * MB);       // VtP [64 bh][128][64][16]
  bf16* Wtq = (bf16*)(ws + 64 * MB);
  bf16* Wtk = Wtq + 512 * 512;
  bf16* Wtv = Wtk + 512 * 512;
  bf16* Wto = Wtv + 512 * 512;
  float2* ctab = (float2*)(ws + 64 * MB + 4 * 512 * 512 * sizeof(bf16));
  bf16* AO = Xb;

  k_conv<<<dim3(Mrows * DM / (256 * 8)), dim3(256), 0, stream>>>(hs, Xb);
  k_transw4<<<dim3(16, 16, 4), dim3(32, 8), 0, stream>>>(Wq, Wk, Wv, Wo, Wtq, Wtk, Wtv, Wto);
  k_ctab<<<dim3(S * 32 / 256), dim3(256), 0, stream>>>(ctab);
  k_gemm_qkv<<<dim3(1536), dim3(256), 0, stream>>>(Xb, Wtq, Wtk, Wtv, Qb, Kb, Vt, ctab);
  k_attn<<<dim3(NBLK * H * 8), dim3(256), 0, stream>>>(Qb, Kb, Vt, AO);
  k_gemm_out<<<dim3(512), dim3(256), 0, stream>>>(AO, Wto, out);
}